// Round 13
// baseline (68.622 us; speedup 1.0000x reference)
//
#include <hip/hip_runtime.h>

// StyleGAN3 filtered_lrelu, fused. R13 = R12 fixed: A loads x direct from
// global with IMAGE-ALIGNED quads (gA = wo0-8+4cq, 4-aligned). Since width
// 128 is a multiple of 4, every quad is fully in- or fully out-of-bounds ->
// one per-quad mask folded into the taps is exact (no element shift), and
// all float4 loads are 16B-aligned. VS2 stored +3-dword-shifted (stride 48)
// so A writes stay uint4-aligned; B consumes dwords 3..15 of 4 b128 reads.
//
// Math (identical to verified R1..R11):
//   fk[t] = f[11-t];  fkU[t] = 2*fk[t]
//   up (per axis): v[i] = sum_{s<6} fkU[2s + (1-(i&1))] * src[(i>>1)+s]
//   leaky relu slope 0.01 between up and down
//   down (per axis): out[o] = sum_{t<12} fk[t] * z[2o+t]
//
// LDS (dwords): VS2@0 [37][48] f16x2 row-parity, halo col c at dword c+3
// (dead after B); ZS@1776 [74][44] f16x2 col-parity (cols>=74 garbage-ok);
// WS@0 [32][44] f16x2 col-parity (VS2 dead by C). total 5032 dw = 20.1 KB
// -> 8 blocks/CU.

#define TAPS 12
#define VS2 0
#define VSS2 48
#define ZS 1776
#define ZSS 44
#define WS 0
#define WSS 44
#define LDS_DW 5032

typedef _Float16 half_t;
typedef half_t h2 __attribute__((ext_vector_type(2)));
typedef __fp16 g2 __attribute__((ext_vector_type(2)));
typedef float f2 __attribute__((ext_vector_type(2)));

__device__ __forceinline__ h2 u2h(unsigned u){ h2 r; __builtin_memcpy(&r, &u, 4); return r; }
__device__ __forceinline__ g2 u2g(unsigned u){ g2 r; __builtin_memcpy(&r, &u, 4); return r; }
__device__ __forceinline__ unsigned h2du(h2 h){ unsigned u; __builtin_memcpy(&u, &h, 4); return u; }
__device__ __forceinline__ unsigned pkrtz_u(float lo, float hi){
    g2 p = __builtin_amdgcn_cvt_pkrtz(lo, hi);
    unsigned u; __builtin_memcpy(&u, &p, 4); return u;
}
__device__ __forceinline__ h2 h2s(float v){ h2 r; r.x = (half_t)v; r.y = r.x; return r; }
__device__ __forceinline__ unsigned pack2(half_t a, half_t b){ h2 t; t.x=a; t.y=b; return h2du(t); }

__global__ __launch_bounds__(256) void flrelu_fused(
    const float* __restrict__ x, const float* __restrict__ f, float* __restrict__ out)
{
    __shared__ float smem[LDS_DW];
    unsigned* smemu = reinterpret_cast<unsigned*>(smem);

    const int tid = threadIdx.x;
    const int nc  = blockIdx.y;
    const int ho0 = (blockIdx.x >> 2) * 32;
    const int wo0 = (blockIdx.x & 3) * 32;

    float fkU[TAPS];
#pragma unroll
    for (int t = 0; t < TAPS; ++t) fkU[t] = 2.0f * f[TAPS - 1 - t];

    const float* xin = x + (size_t)nc * (128 * 128);

    // ---- A: vertical up, x direct from global -> VS2 f16 row-parity pairs ----
    // task=(cq<12, mc<19): v row-pair m=2mc, 2mc+1 at image-aligned quad
    // gA..gA+3 (halo cols 4cq-3..4cq, stored at dwords 4cq..4cq+3).
    // Quad fully in-bounds or fully out (width 128 % 4 == 0): qf folds into
    // taps. Row mask rowf folds per-row. All loads 16B-aligned, clamped.
    if (tid < 228) {
        int cq = tid % 12, mc = tid / 12;
        int gA = wo0 - 8 + 4 * cq;
        float qf = ((unsigned)gA <= 124u) ? 1.f : 0.f;
        int gcc = gA < 0 ? 0 : (gA > 124 ? 124 : gA);
        f2 tap2[6];
#pragma unroll
        for (int s = 0; s < 6; ++s) { tap2[s].x = fkU[2*s+1] * qf; tap2[s].y = fkU[2*s] * qf; }
        f2 acc0[4], acc1[4];
#pragma unroll
        for (int c = 0; c < 4; ++c) { acc0[c].x=0.f; acc0[c].y=0.f; acc1[c].x=0.f; acc1[c].y=0.f; }
#pragma unroll
        for (int s = 0; s < 7; ++s) {
            int gr = ho0 - 5 + 2 * mc + s;
            int grc = gr < 0 ? 0 : (gr > 127 ? 127 : gr);
            float rowf = ((unsigned)gr < 128u) ? 1.f : 0.f;
            float4 xr = *(const float4*)(xin + grc * 128 + gcc);
            if (s < 6) {
                f2 t = tap2[s] * rowf;
                acc0[0] += t * xr.x; acc0[1] += t * xr.y;
                acc0[2] += t * xr.z; acc0[3] += t * xr.w;
            }
            if (s >= 1) {
                f2 t = tap2[s - 1] * rowf;
                acc1[0] += t * xr.x; acc1[1] += t * xr.y;
                acc1[2] += t * xr.z; acc1[3] += t * xr.w;
            }
        }
        int m0 = 2 * mc;
        unsigned* vp0 = smemu + VS2 + m0 * VSS2 + 4 * cq;
        *(uint4*)vp0 = make_uint4(pkrtz_u(acc0[0].x, acc0[0].y),
                                  pkrtz_u(acc0[1].x, acc0[1].y),
                                  pkrtz_u(acc0[2].x, acc0[2].y),
                                  pkrtz_u(acc0[3].x, acc0[3].y));
        if (m0 + 1 < 37) {
            unsigned* vp1 = vp0 + VSS2;
            *(uint4*)vp1 = make_uint4(pkrtz_u(acc1[0].x, acc1[0].y),
                                      pkrtz_u(acc1[1].x, acc1[1].y),
                                      pkrtz_u(acc1[2].x, acc1[2].y),
                                      pkrtz_u(acc1[3].x, acc1[3].y));
        }
    }
    __syncthreads();

    // ---- B: horizontal up + lrelu (VS2 f16 -> ZS f16), packed f16 FMA ----
    // task=(m<37, chunk q<5): z rows 2m,2m+1, cols 16q..16q+15.
    // vc[k] = halo col 8q+k = VS2 dword 8q+3+k (k=0..12).
    if (tid < 185) {
        int q = tid % 5, m = tid / 5;
        const unsigned* vb = smemu + VS2 + m * VSS2 + 8 * q;
        uint4 rr0 = *(const uint4*)(vb);
        uint4 rr1 = *(const uint4*)(vb + 4);
        uint4 rr2 = *(const uint4*)(vb + 8);
        uint4 rr3 = *(const uint4*)(vb + 12);
        h2 vc[13] = { u2h(rr0.w),
                      u2h(rr1.x), u2h(rr1.y), u2h(rr1.z), u2h(rr1.w),
                      u2h(rr2.x), u2h(rr2.y), u2h(rr2.z), u2h(rr2.w),
                      u2h(rr3.x), u2h(rr3.y), u2h(rr3.z), u2h(rr3.w) };
        h2 fo[6], fe[6];
#pragma unroll
        for (int s = 0; s < 6; ++s) { fo[s] = h2s(fkU[2*s+1]); fe[s] = h2s(fkU[2*s]); }
        h2 sl = h2s(0.01f);
        unsigned pk0[8], pk1[8];
#pragma unroll
        for (int h = 0; h < 8; ++h) {        // z cols 16q+2h (even), +1 (odd)
            h2 ae = h2s(0.f), ao = h2s(0.f); // lanes: .x=row 2m, .y=row 2m+1
#pragma unroll
            for (int s = 0; s < 6; ++s) {
                ae += vc[h + s] * fo[s];
                ao += vc[h + s] * fe[s];
            }
            ae = __builtin_elementwise_max(ae, ae * sl);
            ao = __builtin_elementwise_max(ao, ao * sl);
            pk0[h] = pack2(ae.x, ao.x);      // row 2m:   (z_even, z_odd)
            pk1[h] = pack2(ae.y, ao.y);      // row 2m+1: (z_even, z_odd)
        }
        unsigned* z0 = smemu + ZS + (2 * m) * ZSS + 8 * q;
        unsigned* z1 = z0 + ZSS;
        *(uint4*)(z0)     = make_uint4(pk0[0], pk0[1], pk0[2], pk0[3]);
        *(uint4*)(z0 + 4) = make_uint4(pk0[4], pk0[5], pk0[6], pk0[7]);
        *(uint4*)(z1)     = make_uint4(pk1[0], pk1[1], pk1[2], pk1[3]);
        *(uint4*)(z1 + 4) = make_uint4(pk1[4], pk1[5], pk1[6], pk1[7]);
    }
    __syncthreads();

    // ---- C: vertical down (ZS f16 -> WS f16), 4 out rows/task ----
    // task=(col-oct p8<10, row-quad hq<8); reads z rows 8hq..8hq+17.
    if (tid < 80) {
        int p8 = tid % 10, hq = tid / 10;
        h2 fkh[TAPS];
#pragma unroll
        for (int t = 0; t < TAPS; ++t) fkh[t] = h2s(0.5f * fkU[t]);
        h2 acc[4][4];
#pragma unroll
        for (int j = 0; j < 4; ++j)
#pragma unroll
            for (int d = 0; d < 4; ++d) acc[j][d] = h2s(0.f);
        const unsigned* zbase = smemu + ZS + (8 * hq) * ZSS + 4 * p8;
#pragma unroll
        for (int u = 0; u < 18; ++u) {
            uint4 zr = *(const uint4*)(zbase + u * ZSS);
            h2 z0 = u2h(zr.x), z1 = u2h(zr.y), z2 = u2h(zr.z), z3 = u2h(zr.w);
#pragma unroll
            for (int j = 0; j < 4; ++j) {
                int t = u - 2 * j;
                if (t >= 0 && t < TAPS) {
                    h2 tt = fkh[t];
                    acc[j][0] += tt * z0; acc[j][1] += tt * z1;
                    acc[j][2] += tt * z2; acc[j][3] += tt * z3;
                }
            }
        }
        unsigned* wp = smemu + WS + (4 * hq) * WSS + 4 * p8;
#pragma unroll
        for (int j = 0; j < 4; ++j)
            *(uint4*)(wp + j * WSS) = make_uint4(h2du(acc[j][0]), h2du(acc[j][1]),
                                                 h2du(acc[j][2]), h2du(acc[j][3]));
    }
    __syncthreads();

    // ---- D: horizontal down (WS f16 -> global f32) via v_dot2_f32_f16 ----
    {
        int ho = tid >> 3, w4 = tid & 7;
        const unsigned* wp = smemu + WS + ho * WSS + 4 * w4;
        uint4 q0 = *(const uint4*)(wp);
        uint4 q1 = *(const uint4*)(wp + 4);
        unsigned q2 = wp[8];
        unsigned dws[9] = { q0.x, q0.y, q0.z, q0.w, q1.x, q1.y, q1.z, q1.w, q2 };
        unsigned fp[6];
#pragma unroll
        for (int d = 0; d < 6; ++d) fp[d] = pkrtz_u(0.5f * fkU[2*d], 0.5f * fkU[2*d+1]);
        float o[4];
#pragma unroll
        for (int v = 0; v < 4; ++v) {
            float acc = 0.f;
#pragma unroll
            for (int d = 0; d < 6; ++d)
                acc = __builtin_amdgcn_fdot2(u2g(dws[v + d]), u2g(fp[d]), acc, false);
            o[v] = acc;
        }
        *(float4*)(out + ((size_t)nc * 128 + (ho0 + ho)) * 128 + wo0 + 4 * w4)
            = make_float4(o[0], o[1], o[2], o[3]);
    }
}

extern "C" void kernel_launch(void* const* d_in, const int* in_sizes, int n_in,
                              void* d_out, int out_size, void* d_ws, size_t ws_size,
                              hipStream_t stream) {
    const float* x = (const float*)d_in[0];
    const float* f = (const float*)d_in[1];
    float* out = (float*)d_out;
    dim3 grid(16, 1024);
    flrelu_fused<<<grid, 256, 0, stream>>>(x, f, out);
}

// Round 14
// 65.661 us; speedup vs baseline: 1.0451x; 1.0451x over previous
//
#include <hip/hip_runtime.h>

// StyleGAN3 filtered_lrelu, fused. R14 = R11 skeleton + bank-conflict fixes
// via row-dependent slot rotation (stride changes alone can't fix task
// layouts with row-step x quads/row == 0 mod 8 -- R13's lesson):
//   ZS: stride 40, row r's 8-dword slot j stored at slot (j + (r>>3)) mod 5.
//       B writes exactly one slot; C uses 3 precomputed segment bases.
//   XS: stride 48, col c stored at (c + 8*(r mod 6)) mod 48. Halo rows step
//       by 6 per thread -> rotation constant per thread (free).
//   VS2/WS: stride 44 (already well-spread).
//
// Math (identical to verified R1..R11):
//   fk[t] = f[11-t];  fkU[t] = 2*fk[t]
//   up (per axis): v[i] = sum_{s<6} fkU[2s + (1-(i&1))] * src[(i>>1)+s]
//   leaky relu slope 0.01 between up and down
//   down (per axis): out[o] = sum_{t<12} fk[t] * z[2o+t]
//
// LDS (dwords): VS2@0 [37][44] f16x2 row-parity (dead after B);
// ZS@1628 [74][40] f16x2 col-parity, slot-rotated (cols>=74 garbage-ok);
// XS@1628 f32 [42][48] rotated (halo; inside ZS region, dead before B);
// WS@0 [32][44] f16x2 col-parity (VS2 dead by C). total 4588 dw = 18.3 KB.

#define TAPS 12
#define VS2 0
#define VSS2 44
#define ZS 1628
#define ZSS 40
#define XS 1628
#define XSS 48
#define WS 0
#define WSS 44
#define LDS_DW 4588

typedef _Float16 half_t;
typedef half_t h2 __attribute__((ext_vector_type(2)));
typedef __fp16 g2 __attribute__((ext_vector_type(2)));
typedef float f2 __attribute__((ext_vector_type(2)));

__device__ __forceinline__ h2 u2h(unsigned u){ h2 r; __builtin_memcpy(&r, &u, 4); return r; }
__device__ __forceinline__ g2 u2g(unsigned u){ g2 r; __builtin_memcpy(&r, &u, 4); return r; }
__device__ __forceinline__ unsigned h2du(h2 h){ unsigned u; __builtin_memcpy(&u, &h, 4); return u; }
__device__ __forceinline__ unsigned pkrtz_u(float lo, float hi){
    g2 p = __builtin_amdgcn_cvt_pkrtz(lo, hi);
    unsigned u; __builtin_memcpy(&u, &p, 4); return u;
}
__device__ __forceinline__ h2 h2s(float v){ h2 r; r.x = (half_t)v; r.y = r.x; return r; }
__device__ __forceinline__ unsigned pack2(half_t a, half_t b){ h2 t; t.x=a; t.y=b; return h2du(t); }

__global__ __launch_bounds__(256) void flrelu_fused(
    const float* __restrict__ x, const float* __restrict__ f, float* __restrict__ out)
{
    __shared__ float smem[LDS_DW];
    unsigned* smemu = reinterpret_cast<unsigned*>(smem);

    const int tid = threadIdx.x;
    const int nc  = blockIdx.y;
    const int ho0 = (blockIdx.x >> 2) * 32;
    const int wo0 = (blockIdx.x & 3) * 32;

    float fkU[TAPS];
#pragma unroll
    for (int t = 0; t < TAPS; ++t) fkU[t] = 2.0f * f[TAPS - 1 - t];

    const float* xin = x + (size_t)nc * (128 * 128);

    // ---- halo load: 42x42 fp32 -> XS (rotated). col c = tid%42, rows r0+6k;
    // rotation (c + 8*(r mod 6)) mod 48 is CONSTANT per thread (r mod 6 = r0).
    if (tid < 252) {
        int c = tid % 42, r0 = tid / 42;      // r0 in 0..5
        int gc = wo0 - 5 + c;
        bool gcok = (unsigned)gc < 128u;
        int gcc = gc < 0 ? 0 : (gc > 127 ? 127 : gc);
        int cp = c + 8 * r0; if (cp >= 48) cp -= 48;
#pragma unroll
        for (int k = 0; k < 7; ++k) {
            int r = r0 + 6 * k;
            int gr = ho0 - 5 + r;
            int grc = gr < 0 ? 0 : (gr > 127 ? 127 : gr);
            float v = xin[grc * 128 + gcc];
            bool ok = gcok && ((unsigned)gr < 128u);
            smem[XS + r * XSS + cp] = ok ? v : 0.f;
        }
    }
    __syncthreads();

    // ---- A: vertical up (XS f32 -> VS2 f16 row-parity pairs). task=(cq<11, mc<19) ----
    // reads rotated XS: row r, logical cols 4cq..4cq+3 at (4cq + 8*(r mod 6)) mod 48.
    if (tid < 209) {
        int cq = tid % 11, mc = tid / 11;
        int e0 = 2 * (mc % 3);                 // (2*mc) mod 6
        float4 xv[7];
#pragma unroll
        for (int s = 0; s < 7; ++s) {
            int r = 2 * mc + s; r = r < 42 ? r : 41;   // clamped row feeds only skipped m
            int e = e0 + s; if (e >= 6) e -= 6;        // (value unused when clamped)
            int col = 4 * cq + 8 * e; if (col >= 48) col -= 48;
            xv[s] = *(const float4*)(smem + XS + r * XSS + col);
        }
        f2 tap2[6];
#pragma unroll
        for (int s = 0; s < 6; ++s) { tap2[s].x = fkU[2*s+1]; tap2[s].y = fkU[2*s]; }
#pragma unroll
        for (int k2 = 0; k2 < 2; ++k2) {
            int m = 2 * mc + k2;
            if (m < 37) {
                f2 acc[4];
#pragma unroll
                for (int c = 0; c < 4; ++c) { acc[c].x = 0.f; acc[c].y = 0.f; }
#pragma unroll
                for (int s = 0; s < 6; ++s) {
                    float4 xr = xv[k2 + s];
                    acc[0] += tap2[s] * xr.x;
                    acc[1] += tap2[s] * xr.y;
                    acc[2] += tap2[s] * xr.z;
                    acc[3] += tap2[s] * xr.w;
                }
                unsigned* vp = smemu + VS2 + m * VSS2 + 4 * cq;
                *(uint4*)vp = make_uint4(pkrtz_u(acc[0].x, acc[0].y),
                                         pkrtz_u(acc[1].x, acc[1].y),
                                         pkrtz_u(acc[2].x, acc[2].y),
                                         pkrtz_u(acc[3].x, acc[3].y));
            }
        }
    }
    __syncthreads();

    // ---- B: horizontal up + lrelu (VS2 f16 -> ZS f16 rotated), packed f16 FMA ----
    // task=(m<37, chunk q<5): z rows 2m,2m+1, cols 16q..16q+15 = slot q,
    // stored at physical slot (q + (m>>2) mod 5) mod 5 (rows 2m,2m+1 share it).
    if (tid < 185) {
        int q = tid % 5, m = tid / 5;
        const unsigned* vb = smemu + VS2 + m * VSS2 + 8 * q;
        uint4 rr0 = *(const uint4*)(vb);
        uint4 rr1 = *(const uint4*)(vb + 4);
        uint4 rr2 = *(const uint4*)(vb + 8);
        uint2 rr3 = *(const uint2*)(vb + 12);
        h2 vc[14] = { u2h(rr0.x), u2h(rr0.y), u2h(rr0.z), u2h(rr0.w),
                      u2h(rr1.x), u2h(rr1.y), u2h(rr1.z), u2h(rr1.w),
                      u2h(rr2.x), u2h(rr2.y), u2h(rr2.z), u2h(rr2.w),
                      u2h(rr3.x), u2h(rr3.y) };
        h2 fo[6], fe[6];
#pragma unroll
        for (int s = 0; s < 6; ++s) { fo[s] = h2s(fkU[2*s+1]); fe[s] = h2s(fkU[2*s]); }
        h2 sl = h2s(0.01f);
        unsigned pk0[8], pk1[8];
#pragma unroll
        for (int h = 0; h < 8; ++h) {        // z cols 16q+2h (even), +1 (odd)
            h2 ae = h2s(0.f), ao = h2s(0.f); // lanes: .x=row 2m, .y=row 2m+1
#pragma unroll
            for (int s = 0; s < 6; ++s) {
                ae += vc[h + s] * fo[s];
                ao += vc[h + s] * fe[s];
            }
            ae = __builtin_elementwise_max(ae, ae * sl);
            ao = __builtin_elementwise_max(ao, ao * sl);
            pk0[h] = pack2(ae.x, ao.x);      // row 2m:   (z_even, z_odd)
            pk1[h] = pack2(ae.y, ao.y);      // row 2m+1: (z_even, z_odd)
        }
        int rb = m >> 2; if (rb >= 5) rb -= 5;       // (m>>2) mod 5
        int slp = q + rb; if (slp >= 5) slp -= 5;    // physical slot
        unsigned* z0 = smemu + ZS + (2 * m) * ZSS + (slp << 3);
        unsigned* z1 = z0 + ZSS;
        *(uint4*)(z0)     = make_uint4(pk0[0], pk0[1], pk0[2], pk0[3]);
        *(uint4*)(z0 + 4) = make_uint4(pk0[4], pk0[5], pk0[6], pk0[7]);
        *(uint4*)(z1)     = make_uint4(pk1[0], pk1[1], pk1[2], pk1[3]);
        *(uint4*)(z1 + 4) = make_uint4(pk1[4], pk1[5], pk1[6], pk1[7]);
    }
    __syncthreads();

    // ---- C: vertical down (ZS f16 rotated -> WS f16), 4 out rows/task ----
    // task=(col-oct p8<10, row-quad hq<8); reads z rows 8hq..8hq+17.
    // logical dword 4p8 = slot j=p8>>1, offset (p8&1)*4; physical base per
    // u-segment k=(row>>3)-hq in {0,1,2}: b[k] = 8*((j + (hq+k)%5)%5) + off.
    if (tid < 80) {
        int p8 = tid % 10, hq = tid / 10;
        int j = p8 >> 1, off = (p8 & 1) << 2;
        int b0, b1, b2;
        {
            int t0 = hq;     if (t0 >= 5) t0 -= 5;
            int t1 = hq + 1; if (t1 >= 5) t1 -= 5;
            int t2 = hq + 2; if (t2 >= 5) t2 -= 5;
            int s0 = j + t0; if (s0 >= 5) s0 -= 5;
            int s1 = j + t1; if (s1 >= 5) s1 -= 5;
            int s2 = j + t2; if (s2 >= 5) s2 -= 5;
            b0 = (s0 << 3) + off; b1 = (s1 << 3) + off; b2 = (s2 << 3) + off;
        }
        h2 fkh[TAPS];
#pragma unroll
        for (int t = 0; t < TAPS; ++t) fkh[t] = h2s(0.5f * fkU[t]);
        h2 acc[4][4];
#pragma unroll
        for (int jj = 0; jj < 4; ++jj)
#pragma unroll
            for (int d = 0; d < 4; ++d) acc[jj][d] = h2s(0.f);
        const unsigned* zrow = smemu + ZS + (8 * hq) * ZSS;
#pragma unroll
        for (int u = 0; u < 18; ++u) {
            int bk = (u < 8) ? b0 : (u < 16 ? b1 : b2);   // compile-time select
            uint4 zr = *(const uint4*)(zrow + u * ZSS + bk);
            h2 z0 = u2h(zr.x), z1 = u2h(zr.y), z2 = u2h(zr.z), z3 = u2h(zr.w);
#pragma unroll
            for (int jj = 0; jj < 4; ++jj) {
                int t = u - 2 * jj;
                if (t >= 0 && t < TAPS) {
                    h2 tt = fkh[t];
                    acc[jj][0] += tt * z0; acc[jj][1] += tt * z1;
                    acc[jj][2] += tt * z2; acc[jj][3] += tt * z3;
                }
            }
        }
        unsigned* wp = smemu + WS + (4 * hq) * WSS + 4 * p8;
#pragma unroll
        for (int jj = 0; jj < 4; ++jj)
            *(uint4*)(wp + jj * WSS) = make_uint4(h2du(acc[jj][0]), h2du(acc[jj][1]),
                                                  h2du(acc[jj][2]), h2du(acc[jj][3]));
    }
    __syncthreads();

    // ---- D: horizontal down (WS f16 -> global f32) via v_dot2_f32_f16 ----
    {
        int ho = tid >> 3, w4 = tid & 7;
        const unsigned* wp = smemu + WS + ho * WSS + 4 * w4;
        uint4 q0 = *(const uint4*)(wp);
        uint4 q1 = *(const uint4*)(wp + 4);
        unsigned q2 = wp[8];
        unsigned dws[9] = { q0.x, q0.y, q0.z, q0.w, q1.x, q1.y, q1.z, q1.w, q2 };
        unsigned fp[6];
#pragma unroll
        for (int d = 0; d < 6; ++d) fp[d] = pkrtz_u(0.5f * fkU[2*d], 0.5f * fkU[2*d+1]);
        float o[4];
#pragma unroll
        for (int v = 0; v < 4; ++v) {
            float acc = 0.f;
#pragma unroll
            for (int d = 0; d < 6; ++d)
                acc = __builtin_amdgcn_fdot2(u2g(dws[v + d]), u2g(fp[d]), acc, false);
            o[v] = acc;
        }
        *(float4*)(out + ((size_t)nc * 128 + (ho0 + ho)) * 128 + wo0 + 4 * w4)
            = make_float4(o[0], o[1], o[2], o[3]);
    }
}

extern "C" void kernel_launch(void* const* d_in, const int* in_sizes, int n_in,
                              void* d_out, int out_size, void* d_ws, size_t ws_size,
                              hipStream_t stream) {
    const float* x = (const float*)d_in[0];
    const float* f = (const float*)d_in[1];
    float* out = (float*)d_out;
    dim3 grid(16, 1024);
    flrelu_fused<<<grid, 256, 0, stream>>>(x, f, out);
}

// Round 15
// 64.777 us; speedup vs baseline: 1.0594x; 1.0137x over previous
//
#include <hip/hip_runtime.h>

// StyleGAN3 filtered_lrelu, fused. R15 = R11 skeleton with stage A reading x
// DIRECTLY from global (halo stage + XS eliminated: -56 wave-DS, -1 barrier),
// with R13's two faults fixed:
//   (1) VS2 stride 52 (13 quads == 5 mod 8): A-write & B-read bank patterns
//       balanced (R13's stride 48 had 24*stride==0 mod 8 -> parity locks).
//   (2) LDS total 4884 dw = 19536 B <= 19968 -> keeps 8 blocks/CU
//       (R13's 20480 B tipped to 7 blocks, occupancy 70->50).
// Aligned-quad scheme: A loads image-aligned float4 (gA = wo0-8+4cq); quad
// fully in- or out-of-bounds (width 128 % 4 == 0) -> one mask folded into
// taps; row mask folded per-row; VS2 phys dword d = halo_col + 3; B reads
// 4 aligned b128 and consumes dwords 3..15.
//
// Math (identical to verified R1..R11):
//   fk[t] = f[11-t];  fkU[t] = 2*fk[t]
//   up (per axis): v[i] = sum_{s<6} fkU[2s + (1-(i&1))] * src[(i>>1)+s]
//   leaky relu slope 0.01 between up and down
//   down (per axis): out[o] = sum_{t<12} fk[t] * z[2o+t]
//
// LDS (dwords): VS2@0 [37][52] f16x2 row-parity, d = halo_col+3 (dead after
// B); ZS@1924 [74][40] f16x2 col-parity (dwords>=37 garbage-ok, D reads <=36);
// WS@0 [32][44] f16x2 col-parity (VS2 dead by C). total 4884 dw = 19.5 KB.

#define TAPS 12
#define VS2 0
#define VSS2 52
#define ZS 1924
#define ZSS 40
#define WS 0
#define WSS 44
#define LDS_DW 4884

typedef _Float16 half_t;
typedef half_t h2 __attribute__((ext_vector_type(2)));
typedef __fp16 g2 __attribute__((ext_vector_type(2)));
typedef float f2 __attribute__((ext_vector_type(2)));

__device__ __forceinline__ h2 u2h(unsigned u){ h2 r; __builtin_memcpy(&r, &u, 4); return r; }
__device__ __forceinline__ g2 u2g(unsigned u){ g2 r; __builtin_memcpy(&r, &u, 4); return r; }
__device__ __forceinline__ unsigned h2du(h2 h){ unsigned u; __builtin_memcpy(&u, &h, 4); return u; }
__device__ __forceinline__ unsigned pkrtz_u(float lo, float hi){
    g2 p = __builtin_amdgcn_cvt_pkrtz(lo, hi);
    unsigned u; __builtin_memcpy(&u, &p, 4); return u;
}
__device__ __forceinline__ h2 h2s(float v){ h2 r; r.x = (half_t)v; r.y = r.x; return r; }
__device__ __forceinline__ unsigned pack2(half_t a, half_t b){ h2 t; t.x=a; t.y=b; return h2du(t); }

__global__ __launch_bounds__(256) void flrelu_fused(
    const float* __restrict__ x, const float* __restrict__ f, float* __restrict__ out)
{
    __shared__ float smem[LDS_DW];
    unsigned* smemu = reinterpret_cast<unsigned*>(smem);

    const int tid = threadIdx.x;
    const int nc  = blockIdx.y;
    const int ho0 = (blockIdx.x >> 2) * 32;
    const int wo0 = (blockIdx.x & 3) * 32;

    float fkU[TAPS];
#pragma unroll
    for (int t = 0; t < TAPS; ++t) fkU[t] = 2.0f * f[TAPS - 1 - t];

    const float* xin = x + (size_t)nc * (128 * 128);

    // ---- A: vertical up, x direct from global -> VS2 f16 row-parity pairs ----
    // task=(cq<12, mc<19): v row-pair m=2mc, 2mc+1 at image-aligned quad
    // gA..gA+3 (= phys dwords 4cq..4cq+3, halo cols 4cq-3..4cq).
    if (tid < 228) {
        int cq = tid % 12, mc = tid / 12;
        int gA = wo0 - 8 + 4 * cq;
        float qf = ((unsigned)gA <= 124u) ? 1.f : 0.f;
        int gcc = gA < 0 ? 0 : (gA > 124 ? 124 : gA);
        f2 tap2[6];
#pragma unroll
        for (int s = 0; s < 6; ++s) { tap2[s].x = fkU[2*s+1] * qf; tap2[s].y = fkU[2*s] * qf; }
        f2 acc0[4], acc1[4];
#pragma unroll
        for (int c = 0; c < 4; ++c) { acc0[c].x=0.f; acc0[c].y=0.f; acc1[c].x=0.f; acc1[c].y=0.f; }
#pragma unroll
        for (int s = 0; s < 7; ++s) {
            int gr = ho0 - 5 + 2 * mc + s;
            int grc = gr < 0 ? 0 : (gr > 127 ? 127 : gr);
            float rowf = ((unsigned)gr < 128u) ? 1.f : 0.f;
            float4 xr = *(const float4*)(xin + grc * 128 + gcc);
            if (s < 6) {
                f2 t = tap2[s] * rowf;
                acc0[0] += t * xr.x; acc0[1] += t * xr.y;
                acc0[2] += t * xr.z; acc0[3] += t * xr.w;
            }
            if (s >= 1) {
                f2 t = tap2[s - 1] * rowf;
                acc1[0] += t * xr.x; acc1[1] += t * xr.y;
                acc1[2] += t * xr.z; acc1[3] += t * xr.w;
            }
        }
        int m0 = 2 * mc;
        unsigned* vp0 = smemu + VS2 + m0 * VSS2 + 4 * cq;
        *(uint4*)vp0 = make_uint4(pkrtz_u(acc0[0].x, acc0[0].y),
                                  pkrtz_u(acc0[1].x, acc0[1].y),
                                  pkrtz_u(acc0[2].x, acc0[2].y),
                                  pkrtz_u(acc0[3].x, acc0[3].y));
        if (m0 + 1 < 37) {
            unsigned* vp1 = vp0 + VSS2;
            *(uint4*)vp1 = make_uint4(pkrtz_u(acc1[0].x, acc1[0].y),
                                      pkrtz_u(acc1[1].x, acc1[1].y),
                                      pkrtz_u(acc1[2].x, acc1[2].y),
                                      pkrtz_u(acc1[3].x, acc1[3].y));
        }
    }
    __syncthreads();

    // ---- B: horizontal up + lrelu (VS2 f16 -> ZS f16), packed f16 FMA ----
    // task=(m<37, chunk q<5): z rows 2m,2m+1, cols 16q..16q+15.
    // vc[k] = halo col 8q+k = VS2 phys dword 8q+3+k (k=0..12).
    if (tid < 185) {
        int q = tid % 5, m = tid / 5;
        const unsigned* vb = smemu + VS2 + m * VSS2 + 8 * q;
        uint4 rr0 = *(const uint4*)(vb);
        uint4 rr1 = *(const uint4*)(vb + 4);
        uint4 rr2 = *(const uint4*)(vb + 8);
        uint4 rr3 = *(const uint4*)(vb + 12);
        h2 vc[13] = { u2h(rr0.w),
                      u2h(rr1.x), u2h(rr1.y), u2h(rr1.z), u2h(rr1.w),
                      u2h(rr2.x), u2h(rr2.y), u2h(rr2.z), u2h(rr2.w),
                      u2h(rr3.x), u2h(rr3.y), u2h(rr3.z), u2h(rr3.w) };
        h2 fo[6], fe[6];
#pragma unroll
        for (int s = 0; s < 6; ++s) { fo[s] = h2s(fkU[2*s+1]); fe[s] = h2s(fkU[2*s]); }
        h2 sl = h2s(0.01f);
        unsigned pk0[8], pk1[8];
#pragma unroll
        for (int h = 0; h < 8; ++h) {        // z cols 16q+2h (even), +1 (odd)
            h2 ae = h2s(0.f), ao = h2s(0.f); // lanes: .x=row 2m, .y=row 2m+1
#pragma unroll
            for (int s = 0; s < 6; ++s) {
                ae += vc[h + s] * fo[s];
                ao += vc[h + s] * fe[s];
            }
            ae = __builtin_elementwise_max(ae, ae * sl);
            ao = __builtin_elementwise_max(ao, ao * sl);
            pk0[h] = pack2(ae.x, ao.x);      // row 2m:   (z_even, z_odd)
            pk1[h] = pack2(ae.y, ao.y);      // row 2m+1: (z_even, z_odd)
        }
        unsigned* z0 = smemu + ZS + (2 * m) * ZSS + 8 * q;
        unsigned* z1 = z0 + ZSS;
        *(uint4*)(z0)     = make_uint4(pk0[0], pk0[1], pk0[2], pk0[3]);
        *(uint4*)(z0 + 4) = make_uint4(pk0[4], pk0[5], pk0[6], pk0[7]);
        *(uint4*)(z1)     = make_uint4(pk1[0], pk1[1], pk1[2], pk1[3]);
        *(uint4*)(z1 + 4) = make_uint4(pk1[4], pk1[5], pk1[6], pk1[7]);
    }
    __syncthreads();

    // ---- C: vertical down (ZS f16 -> WS f16), 4 out rows/task ----
    // task=(col-oct p8<10, row-quad hq<8); reads z rows 8hq..8hq+17.
    if (tid < 80) {
        int p8 = tid % 10, hq = tid / 10;
        h2 fkh[TAPS];
#pragma unroll
        for (int t = 0; t < TAPS; ++t) fkh[t] = h2s(0.5f * fkU[t]);
        h2 acc[4][4];
#pragma unroll
        for (int j = 0; j < 4; ++j)
#pragma unroll
            for (int d = 0; d < 4; ++d) acc[j][d] = h2s(0.f);
        const unsigned* zbase = smemu + ZS + (8 * hq) * ZSS + 4 * p8;
#pragma unroll
        for (int u = 0; u < 18; ++u) {
            uint4 zr = *(const uint4*)(zbase + u * ZSS);
            h2 z0 = u2h(zr.x), z1 = u2h(zr.y), z2 = u2h(zr.z), z3 = u2h(zr.w);
#pragma unroll
            for (int j = 0; j < 4; ++j) {
                int t = u - 2 * j;
                if (t >= 0 && t < TAPS) {
                    h2 tt = fkh[t];
                    acc[j][0] += tt * z0; acc[j][1] += tt * z1;
                    acc[j][2] += tt * z2; acc[j][3] += tt * z3;
                }
            }
        }
        unsigned* wp = smemu + WS + (4 * hq) * WSS + 4 * p8;
#pragma unroll
        for (int j = 0; j < 4; ++j)
            *(uint4*)(wp + j * WSS) = make_uint4(h2du(acc[j][0]), h2du(acc[j][1]),
                                                 h2du(acc[j][2]), h2du(acc[j][3]));
    }
    __syncthreads();

    // ---- D: horizontal down (WS f16 -> global f32) via v_dot2_f32_f16 ----
    {
        int ho = tid >> 3, w4 = tid & 7;
        const unsigned* wp = smemu + WS + ho * WSS + 4 * w4;
        uint4 q0 = *(const uint4*)(wp);
        uint4 q1 = *(const uint4*)(wp + 4);
        unsigned q2 = wp[8];
        unsigned dws[9] = { q0.x, q0.y, q0.z, q0.w, q1.x, q1.y, q1.z, q1.w, q2 };
        unsigned fp[6];
#pragma unroll
        for (int d = 0; d < 6; ++d) fp[d] = pkrtz_u(0.5f * fkU[2*d], 0.5f * fkU[2*d+1]);
        float o[4];
#pragma unroll
        for (int v = 0; v < 4; ++v) {
            float acc = 0.f;
#pragma unroll
            for (int d = 0; d < 6; ++d)
                acc = __builtin_amdgcn_fdot2(u2g(dws[v + d]), u2g(fp[d]), acc, false);
            o[v] = acc;
        }
        *(float4*)(out + ((size_t)nc * 128 + (ho0 + ho)) * 128 + wo0 + 4 * w4)
            = make_float4(o[0], o[1], o[2], o[3]);
    }
}

extern "C" void kernel_launch(void* const* d_in, const int* in_sizes, int n_in,
                              void* d_out, int out_size, void* d_ws, size_t ws_size,
                              hipStream_t stream) {
    const float* x = (const float*)d_in[0];
    const float* f = (const float*)d_in[1];
    float* out = (float*)d_out;
    dim3 grid(16, 1024);
    flrelu_fused<<<grid, 256, 0, stream>>>(x, f, out);
}